// Round 3
// baseline (239.241 us; speedup 1.0000x reference)
//
#include <hip/hip_runtime.h>

// LSHAttention: reference returns ONLY sticker = argsort(buckets) [B,S] int32.
// B=4, S=4096, D=1024, NR=32, 64 buckets.
// k1: one block per 64-token chunk (1024 thr). Lane = 4 tokens x 16-way k-split.
//     Q global->reg (read once, coalesced), R from L1/L2 (512 KB, broadcast),
//     32 acc/lane (no spill), shfl_xor butterfly reduce, in-register argmax,
//     LDS histogram. No partial buffers, no barriers in the hot loop.
// k2: offset scan; k3: stable scatter (both verified absmax 0 in round 1).

#define B_DIM 4
#define S_LEN 4096
#define D_DIM 1024
#define NR 32
#define NBK 64
#define TM 64
#define NCHUNK (S_LEN / TM)   // 64

__global__ __launch_bounds__(1024) void k1_buckets(
    const float* __restrict__ Q, const float* __restrict__ R,
    int* __restrict__ buckets, int* __restrict__ hist)
{
    __shared__ int cnt[NBK];

    const int t = threadIdx.x;
    const int b = blockIdx.x >> 6;
    const int chunk = blockIdx.x & 63;
    const int wave = t >> 6;          // 16 waves
    const int lane = t & 63;
    const int tok4 = lane >> 4;       // 4 tokens per wave
    const int l = lane & 15;          // 16-way k split within wave

    const int wtok = wave * 4 + tok4;        // token within chunk [0,64)
    const int gtok = chunk * TM + wtok;      // token within batch

    if (t < NBK) cnt[t] = 0;

    const float* Qrow = Q + ((size_t)b * S_LEN + gtok) * D_DIM;
    const float* Rb   = R + (size_t)b * D_DIM * NR;

    float4 acc[8];
#pragma unroll
    for (int rc = 0; rc < 8; ++rc) acc[rc] = make_float4(0.f, 0.f, 0.f, 0.f);

    // k-loop: lane l covers k in {s*64 + l*4 .. +4}, s = 0..15  (64 k per lane)
    for (int s = 0; s < 16; ++s) {
        const int k0 = s * 64 + l * 4;
        const float4 q = *reinterpret_cast<const float4*>(Qrow + k0);
        const float qv[4] = {q.x, q.y, q.z, q.w};
        const float* rp = Rb + (size_t)k0 * NR;
#pragma unroll
        for (int kk = 0; kk < 4; ++kk) {
            const float qk = qv[kk];
            const float4* rrow = reinterpret_cast<const float4*>(rp + kk * NR);
#pragma unroll
            for (int rc = 0; rc < 8; ++rc) {
                const float4 rv = rrow[rc];
                acc[rc].x = fmaf(qk, rv.x, acc[rc].x);
                acc[rc].y = fmaf(qk, rv.y, acc[rc].y);
                acc[rc].z = fmaf(qk, rv.z, acc[rc].z);
                acc[rc].w = fmaf(qk, rv.w, acc[rc].w);
            }
        }
    }

    // butterfly all-reduce over the 16 k-split lanes (low 4 lane bits)
#pragma unroll
    for (int rc = 0; rc < 8; ++rc) {
#pragma unroll
        for (int off = 1; off < 16; off <<= 1) {
            acc[rc].x += __shfl_xor(acc[rc].x, off, 64);
            acc[rc].y += __shfl_xor(acc[rc].y, off, 64);
            acc[rc].z += __shfl_xor(acc[rc].z, off, 64);
            acc[rc].w += __shfl_xor(acc[rc].w, off, 64);
        }
    }

    // in-register argmax(concat[xR,-xR]) with first-occurrence tie-break
    float xv[NR];
#pragma unroll
    for (int rc = 0; rc < 8; ++rc) {
        xv[rc * 4 + 0] = acc[rc].x;
        xv[rc * 4 + 1] = acc[rc].y;
        xv[rc * 4 + 2] = acc[rc].z;
        xv[rc * 4 + 3] = acc[rc].w;
    }
    float m1 = xv[0]; int i1 = 0;
    float m2 = xv[0]; int i2 = 0;
#pragma unroll
    for (int r = 1; r < NR; ++r) {
        const float v = xv[r];
        if (v > m1) { m1 = v; i1 = r; }
        if (v < m2) { m2 = v; i2 = r; }
    }
    const int bk = (m1 >= -m2) ? i1 : (NR + i2);

    __syncthreads();                 // cnt init visible; all waves arrived
    if (l == 0) {
        buckets[(size_t)b * S_LEN + gtok] = bk;
        atomicAdd(&cnt[bk], 1);
    }
    __syncthreads();
    if (t < NBK) hist[((size_t)b * NCHUNK + chunk) * NBK + t] = cnt[t];
}

// One block, 256 threads: thread = (batch b = t/64, bucket bk = t%64).
__global__ __launch_bounds__(256) void k2_scan(
    const int* __restrict__ hist, int* __restrict__ chunkOffset)
{
    const int t = threadIdx.x;
    const int b = t >> 6;
    const int bk = t & 63;
    const int lane = t & 63;

    int total = 0;
    for (int c = 0; c < NCHUNK; ++c)
        total += hist[((size_t)b * NCHUNK + c) * NBK + bk];

    int incl = total;
#pragma unroll
    for (int off = 1; off < 64; off <<= 1) {
        int n = __shfl_up(incl, off, 64);
        if (lane >= off) incl += n;
    }
    int run = incl - total;   // exclusive prefix over buckets = bucketStart

    for (int c = 0; c < NCHUNK; ++c) {
        int h = hist[((size_t)b * NCHUNK + c) * NBK + bk];
        chunkOffset[((size_t)b * NCHUNK + c) * NBK + bk] = run;
        run += h;
    }
}

// Stable scatter: wave = 64 consecutive tokens (one chunk).
__global__ __launch_bounds__(256) void k3_scatter(
    const int* __restrict__ buckets, const int* __restrict__ chunkOffset,
    int* __restrict__ out)
{
    const int gid = blockIdx.x * 256 + threadIdx.x;  // 0..16383
    const int b = gid >> 12;
    const int s = gid & (S_LEN - 1);
    const int chunk = s >> 6;
    const int lane = threadIdx.x & 63;

    const int bk = buckets[gid];

    unsigned long long m = ~0ull;
#pragma unroll
    for (int i = 0; i < 6; ++i) {
        unsigned long long bi = __ballot((bk >> i) & 1);
        m &= ((bk >> i) & 1) ? bi : ~bi;
    }
    int rank = __popcll(m & ((1ull << lane) - 1ull));

    int pos = chunkOffset[((size_t)b * NCHUNK + chunk) * NBK + bk] + rank;
    out[(size_t)b * S_LEN + pos] = s;
}

extern "C" void kernel_launch(void* const* d_in, const int* in_sizes, int n_in,
                              void* d_out, int out_size, void* d_ws, size_t ws_size,
                              hipStream_t stream) {
    const float* Q = (const float*)d_in[0];
    // d_in[1] = key, d_in[2] = value: dead code in the reference, never read.
    const float* R = (const float*)d_in[3];

    int* buckets     = (int*)d_ws;                      // 16384 ints
    int* hist        = buckets + B_DIM * S_LEN;         // 16384 ints
    int* chunkOffset = hist + B_DIM * NCHUNK * NBK;     // 16384 ints

    k1_buckets<<<B_DIM * NCHUNK, 1024, 0, stream>>>(Q, R, buckets, hist);
    k2_scan   <<<1,              256,  0, stream>>>(hist, chunkOffset);
    k3_scatter<<<(B_DIM * S_LEN) / 256, 256, 0, stream>>>(buckets, chunkOffset, (int*)d_out);
}

// Round 4
// 46.166 us; speedup vs baseline: 5.1822x; 5.1822x over previous
//
#include <hip/hip_runtime.h>

// LSHAttention: reference returns ONLY sticker = argsort(buckets) [B,S] int32.
// B=4, S=4096, D=1024, NR=32, 64 buckets.
// k1: block = 1024 thr = 16 waves = one 64-token chunk.
//     lane = token, wave w = k-slice [w*64, w*64+64).
//     R read via WAVE-UNIFORM index (readfirstlane) -> scalar loads (SMEM pipe,
//     SGPR operand in v_fma) -- no LDS, no VMEM divergence for R.
//     Q global->reg bursts (two 128B lines/lane), read exactly once.
//     16-way k-slice combine in LDS, wave 0 argmax + bucket + chunk hist.
// k2: offset scan; k3: stable scatter (verified absmax 0 in rounds 1-3).

#define B_DIM 4
#define S_LEN 4096
#define D_DIM 1024
#define NR 32
#define NBK 64
#define TM 64
#define NCHUNK (S_LEN / TM)   // 64
#define NW 16                 // waves per block = k-slices
#define KSLICE (D_DIM / NW)   // 64 k per wave

__global__ __launch_bounds__(1024, 4) void k1_buckets(
    const float* __restrict__ Q, const float* __restrict__ R,
    int* __restrict__ buckets, int* __restrict__ hist)
{
    __shared__ float buf[NW][NR][TM];   // 128 KB combine buffer
    __shared__ int cnt[NBK];

    const int t = threadIdx.x;
    const int b = blockIdx.x >> 6;
    const int chunk = blockIdx.x & 63;
    const int lane = t & 63;
    const int w = __builtin_amdgcn_readfirstlane(t >> 6);  // wave-uniform k-slice

    const int gtok = chunk * TM + lane;                    // token (one per lane)
    const float* Qrow = Q + ((size_t)b * S_LEN + gtok) * D_DIM + w * KSLICE;
    const float4* R4 = reinterpret_cast<const float4*>(
        R + (size_t)b * D_DIM * NR) + (size_t)w * KSLICE * (NR / 4);

    float4 acc[8];
#pragma unroll
    for (int rc = 0; rc < 8; ++rc) acc[rc] = make_float4(0.f, 0.f, 0.f, 0.f);

    // two phases of 32 k each: one 128B Q line per lane per phase
#pragma unroll
    for (int ph = 0; ph < 2; ++ph) {
        float4 qv[8];
#pragma unroll
        for (int j = 0; j < 8; ++j)
            qv[j] = *reinterpret_cast<const float4*>(Qrow + ph * 32 + j * 4);

#pragma unroll
        for (int kk = 0; kk < 32; ++kk) {
            const int k = ph * 32 + kk;             // compile-time within unroll
            const float4 qq = qv[kk >> 2];
            const float qk = ((kk & 3) == 0) ? qq.x
                           : ((kk & 3) == 1) ? qq.y
                           : ((kk & 3) == 2) ? qq.z : qq.w;
            // uniform index -> s_load; value lands in SGPR, v_fma takes it
#pragma unroll
            for (int rc = 0; rc < 8; ++rc) {
                const float4 rv = R4[k * 8 + rc];
                acc[rc].x = fmaf(qk, rv.x, acc[rc].x);
                acc[rc].y = fmaf(qk, rv.y, acc[rc].y);
                acc[rc].z = fmaf(qk, rv.z, acc[rc].z);
                acc[rc].w = fmaf(qk, rv.w, acc[rc].w);
            }
        }
    }

    // stage per-wave partials: buf[w][r][token], lane-consecutive (no conflicts)
#pragma unroll
    for (int rc = 0; rc < 8; ++rc) {
        buf[w][rc * 4 + 0][lane] = acc[rc].x;
        buf[w][rc * 4 + 1][lane] = acc[rc].y;
        buf[w][rc * 4 + 2][lane] = acc[rc].z;
        buf[w][rc * 4 + 3][lane] = acc[rc].w;
    }
    if (t < NBK) cnt[t] = 0;
    __syncthreads();

    if (t < TM) {
        float x[NR];
#pragma unroll
        for (int r = 0; r < NR; ++r) {
            float s = 0.f;
#pragma unroll
            for (int ww = 0; ww < NW; ++ww) s += buf[ww][r][t];
            x[r] = s;
        }
        // argmax(concat[xR,-xR]) with first-occurrence tie-break
        float m1 = x[0]; int i1 = 0;
        float m2 = x[0]; int i2 = 0;
#pragma unroll
        for (int r = 1; r < NR; ++r) {
            const float v = x[r];
            if (v > m1) { m1 = v; i1 = r; }
            if (v < m2) { m2 = v; i2 = r; }
        }
        const int bk = (m1 >= -m2) ? i1 : (NR + i2);
        buckets[(size_t)b * S_LEN + chunk * TM + t] = bk;
        atomicAdd(&cnt[bk], 1);
    }
    __syncthreads();
    if (t < NBK) hist[((size_t)b * NCHUNK + chunk) * NBK + t] = cnt[t];
}

// One block, 256 threads: thread = (batch b = t/64, bucket bk = t%64).
__global__ __launch_bounds__(256) void k2_scan(
    const int* __restrict__ hist, int* __restrict__ chunkOffset)
{
    const int t = threadIdx.x;
    const int b = t >> 6;
    const int bk = t & 63;
    const int lane = t & 63;

    int total = 0;
    for (int c = 0; c < NCHUNK; ++c)
        total += hist[((size_t)b * NCHUNK + c) * NBK + bk];

    int incl = total;
#pragma unroll
    for (int off = 1; off < 64; off <<= 1) {
        int n = __shfl_up(incl, off, 64);
        if (lane >= off) incl += n;
    }
    int run = incl - total;   // exclusive prefix over buckets = bucketStart

    for (int c = 0; c < NCHUNK; ++c) {
        int h = hist[((size_t)b * NCHUNK + c) * NBK + bk];
        chunkOffset[((size_t)b * NCHUNK + c) * NBK + bk] = run;
        run += h;
    }
}

// Stable scatter: wave = 64 consecutive tokens (one chunk).
__global__ __launch_bounds__(256) void k3_scatter(
    const int* __restrict__ buckets, const int* __restrict__ chunkOffset,
    int* __restrict__ out)
{
    const int gid = blockIdx.x * 256 + threadIdx.x;  // 0..16383
    const int b = gid >> 12;
    const int s = gid & (S_LEN - 1);
    const int chunk = s >> 6;
    const int lane = threadIdx.x & 63;

    const int bk = buckets[gid];

    unsigned long long m = ~0ull;
#pragma unroll
    for (int i = 0; i < 6; ++i) {
        unsigned long long bi = __ballot((bk >> i) & 1);
        m &= ((bk >> i) & 1) ? bi : ~bi;
    }
    int rank = __popcll(m & ((1ull << lane) - 1ull));

    int pos = chunkOffset[((size_t)b * NCHUNK + chunk) * NBK + bk] + rank;
    out[(size_t)b * S_LEN + pos] = s;
}

extern "C" void kernel_launch(void* const* d_in, const int* in_sizes, int n_in,
                              void* d_out, int out_size, void* d_ws, size_t ws_size,
                              hipStream_t stream) {
    const float* Q = (const float*)d_in[0];
    // d_in[1] = key, d_in[2] = value: dead code in the reference, never read.
    const float* R = (const float*)d_in[3];

    int* buckets     = (int*)d_ws;                      // 16384 ints
    int* hist        = buckets + B_DIM * S_LEN;         // 16384 ints
    int* chunkOffset = hist + B_DIM * NCHUNK * NBK;     // 16384 ints

    k1_buckets<<<B_DIM * NCHUNK, 1024, 0, stream>>>(Q, R, buckets, hist);
    k2_scan   <<<1,              256,  0, stream>>>(hist, chunkOffset);
    k3_scatter<<<(B_DIM * S_LEN) / 256, 256, 0, stream>>>(buckets, chunkOffset, (int*)d_out);
}